// Round 6
// baseline (477.470 us; speedup 1.0000x reference)
//
#include <hip/hip_runtime.h>

#define NVERT 40000

// Per-block LDS (~39.3 KB -> 4 blocks/CU):
//   sW[4544] f32: WQ[8][8][9] @0 | WK[8][8][8] @576 | WV[6][8][8][9] @1088
//   sFb[4][2112] ushort: per-wave, 32 rows x 66-ushort stride; holds ptm (bf16)
//                        during transport, then f (bf16) [row n: pos c*8+i]
//   sAtt[4][256] f32: per-neighbor coefs [a, a*u0, a*u1, a*u0^2, 2a*u0u1, a*u1^2]
//   sQ[4][8] f32
// Register discipline (R5 lesson): true need must be < the launch_bounds cap.
// Empirical hipcc mapping: __launch_bounds__(256,2) -> 128 VGPR cap (R1),
// (256,4) -> 64 (R2/R3, heavy spill). Uncapped -> 156 -> rounds to 192 granule
// -> only 2 waves/SIMD. This version keeps x and f in packed-bf16 u32 regs
// (16+16 u32 instead of 32+32 f32) so need ~100 < 128: no spill AND 4 waves/SIMD.

__device__ __forceinline__ void wave_lds_fence() {
  asm volatile("s_waitcnt lgkmcnt(0)" ::: "memory");
}

// fast bf16 round (round-half-up via +0x8000 truncate; inputs finite)
__device__ __forceinline__ unsigned int pack_bf2(float a, float b) {
  return ((__float_as_uint(a) + 0x8000u) >> 16) |
         ((__float_as_uint(b) + 0x8000u) & 0xFFFF0000u);
}
__device__ __forceinline__ float bf_lo(unsigned int u) { return __uint_as_float(u << 16); }
__device__ __forceinline__ float bf_hi(unsigned int u) { return __uint_as_float(u & 0xFFFF0000u); }

__global__ __launch_bounds__(256, 2)
void ge_attn(const float* __restrict__ x,
             const int* __restrict__ nbr,
             const void* __restrict__ maskp,
             const float* __restrict__ ptm,
             const float* __restrict__ rpu,
             const float* __restrict__ rbasis,
             const float* __restrict__ qcoef,
             const float* __restrict__ kcoef,
             const float* __restrict__ vb0,
             const float* __restrict__ vb1,
             const float* __restrict__ vb2,
             const float* __restrict__ vp0,
             const float* __restrict__ vp1,
             const float* __restrict__ vp2,
             float* __restrict__ out)
{
  __shared__ float sW[4544];
  __shared__ unsigned short sFb[4][2112];
  __shared__ float sAtt[4][256];
  __shared__ float sQ[4][8];
  __shared__ int sFlagB, sFlagF;

  const int tid  = threadIdx.x;
  const int wv   = tid >> 6;
  const int lane = tid & 63;

  if (tid == 0) { sFlagB = 0; sFlagF = 0; }
  __syncthreads();

  // ---- mask dtype probe (bool bytes vs int32 vs float32), deterministic ----
  {
    const unsigned int* mw = (const unsigned int*)maskp;
    int b0 = 0, b1 = 0;
#pragma unroll
    for (int t = 0; t < 8; ++t) {
      const unsigned int w = mw[tid + (t << 8)];
      b1 |= (w == 0x3F800000u) ? 1 : 0;
      b0 |= (w > 1u && w != 0x3F800000u) ? 1 : 0;
    }
    if (b0) sFlagB = 1;   // packed bool bytes
    if (b1) sFlagF = 1;   // float 1.0f pattern
  }

  // ---- per-block W precompute into LDS ----
  for (int r = tid; r < 512; r += 256) {
    const int m = r >> 6;
    const int c = (r >> 3) & 7;
    const int i = r & 7;
    const float* par; const float* bas; int ospan, oo;
    switch (m) {
      case 0:  par = qcoef; bas = rbasis; ospan = 1; oo = 0; break;
      case 1:  par = kcoef; bas = rbasis; ospan = 1; oo = 0; break;
      case 2:  par = vp0;   bas = vb0;    ospan = 1; oo = 0; break;
      case 3:  par = vp1;   bas = vb1;    ospan = 2; oo = 0; break;
      case 4:  par = vp1;   bas = vb1;    ospan = 2; oo = 1; break;
      case 5:  par = vp2;   bas = vb2;    ospan = 3; oo = 0; break;
      case 6:  par = vp2;   bas = vb2;    ospan = 3; oo = 1; break;
      default: par = vp2;   bas = vb2;    ospan = 3; oo = 2; break;
    }
    float acc[8] = {0,0,0,0,0,0,0,0};
#pragma unroll
    for (int b = 0; b < 8; ++b) {
      const float cf = par[c*8 + b];
      const float* row = bas + (((b*ospan + oo)*8 + i) << 3);
#pragma unroll
      for (int j = 0; j < 8; ++j) acc[j] += cf * row[j];
    }
    float* dst;
    if (m == 1)      dst = sW + 576 + ((c*8 + i) << 3);
    else if (m == 0) dst = sW + (c*8 + i)*9;
    else             dst = sW + 1088 + (m - 2)*576 + (c*8 + i)*9;
#pragma unroll
    for (int j = 0; j < 8; ++j) dst[j] = acc[j];
  }
  __syncthreads();   // last block-wide barrier; LDS sharing below is intra-wave

  const int mode = sFlagB ? 1 : (sFlagF ? 2 : 0);

  const int v = (blockIdx.x << 2) + wv;   // grid is exactly NVERT/4
  const int n = lane >> 1;                // neighbor 0..31
  const int h = lane & 1;                 // channel half
  const int cbase = h << 2;
  unsigned short* sFw = sFb[wv];

  // ---- independent small loads ----
  const int nbv = nbr[(v << 5) + n];
  const int mi = (v << 5) + n;
  const float2 uu = *(const float2*)(rpu + ((size_t)mi << 1));
  bool mk;
  if (mode == 1)      mk = ((const unsigned char*)maskp)[mi] != 0;
  else if (mode == 2) mk = ((((const unsigned int*)maskp)[mi]) & 0x7FFFFFFFu) != 0u;
  else                mk = ((const int*)maskp)[mi] != 0;

  // ---- stage ptm[v] (8KB) coalesced, converting to bf16 in padded rows ----
  {
    const float4* p4 = (const float4*)(ptm + (size_t)v * 2048);
#pragma unroll
    for (int t = 0; t < 8; ++t) {
      const int g = lane + (t << 6);
      const float4 val = p4[g];              // 1KB contiguous per instruction
      const int row = g >> 4;
      const int rr  = g & 15;
      uint2 pk;
      pk.x = pack_bf2(val.x, val.y);
      pk.y = pack_bf2(val.z, val.w);
      *(uint2*)&sFw[row*66 + (rr << 2)] = pk;
    }
  }

  // ---- gather neighbor features, packed bf16 (16 u32 regs, not 32 f32) ----
  unsigned int xnpk[4][4];
  {
    const float* xb = x + ((size_t)nbv << 6) + (cbase << 3);
#pragma unroll
    for (int c4 = 0; c4 < 4; ++c4) {
      const float4 a = *(const float4*)(xb + (c4 << 3));
      const float4 b = *(const float4*)(xb + (c4 << 3) + 4);
      xnpk[c4][0] = pack_bf2(a.x, a.y);
      xnpk[c4][1] = pack_bf2(a.z, a.w);
      xnpk[c4][2] = pack_bf2(b.x, b.y);
      xnpk[c4][3] = pack_bf2(b.z, b.w);
    }
  }

  wave_lds_fence();   // staging (this wave's writes) complete

  // ---- transport: f[c,i] = ptm_row(n,i) . xn[c], accumulated into packed fpk ----
  unsigned int fpk[4][4];
  float fprev[4];
#pragma unroll
  for (int i = 0; i < 8; ++i) {
    const uint4 r = *(const uint4*)&sFw[n*66 + (i << 3)];
    const float p0 = bf_lo(r.x), p1 = bf_hi(r.x);
    const float p2 = bf_lo(r.y), p3 = bf_hi(r.y);
    const float p4 = bf_lo(r.z), p5 = bf_hi(r.z);
    const float p6 = bf_lo(r.w), p7 = bf_hi(r.w);
#pragma unroll
    for (int c4 = 0; c4 < 4; ++c4) {
      const float acc =
          p0*bf_lo(xnpk[c4][0]) + p1*bf_hi(xnpk[c4][0])
        + p2*bf_lo(xnpk[c4][1]) + p3*bf_hi(xnpk[c4][1])
        + p4*bf_lo(xnpk[c4][2]) + p5*bf_hi(xnpk[c4][2])
        + p6*bf_lo(xnpk[c4][3]) + p7*bf_hi(xnpk[c4][3]);
      if ((i & 1) == 0) fprev[c4] = acc;
      else              fpk[c4][i >> 1] = pack_bf2(fprev[c4], acc);
    }
  }

  // ---- K partial from packed f (unpack per c4, transient 8 f32) ----
  float Kp[8] = {0,0,0,0,0,0,0,0};
#pragma unroll
  for (int c4 = 0; c4 < 4; ++c4) {
    float fc[8];
#pragma unroll
    for (int q = 0; q < 4; ++q) {
      fc[2*q]     = bf_lo(fpk[c4][q]);
      fc[2*q + 1] = bf_hi(fpk[c4][q]);
    }
    const float* wk = sW + 576 + ((cbase + c4) << 6);
#pragma unroll
    for (int i = 0; i < 8; ++i) {
      const float4 wa = *(const float4*)(wk + (i << 3));
      const float4 wb = *(const float4*)(wk + (i << 3) + 4);
      Kp[i] += wa.x*fc[0] + wa.y*fc[1] + wa.z*fc[2] + wa.w*fc[3]
             + wb.x*fc[4] + wb.y*fc[5] + wb.z*fc[6] + wb.w*fc[7];
    }
  }

  // ---- write packed f over the ptm rows (same-wave DS in-order => safe) ----
#pragma unroll
  for (int c4 = 0; c4 < 4; ++c4) {
    *(uint4*)&sFw[n*66 + ((cbase + c4) << 3)] =
        make_uint4(fpk[c4][0], fpk[c4][1], fpk[c4][2], fpk[c4][3]);
  }

  // ---- Q (lane=(c,i) mapping) ----
  {
    const int qc_ = lane >> 3;
    const int qi  = lane & 7;
    const float* xvr = x + ((size_t)v << 6) + (qc_ << 3);
    const float4 xa  = *(const float4*)xvr;
    const float4 xb2 = *(const float4*)(xvr + 4);
    const float* wq = sW + (qc_*8 + qi)*9;
    float qa = wq[0]*xa.x + wq[1]*xa.y + wq[2]*xa.z + wq[3]*xa.w
             + wq[4]*xb2.x + wq[5]*xb2.y + wq[6]*xb2.z + wq[7]*xb2.w;
    qa += __shfl_xor(qa, 8);
    qa += __shfl_xor(qa, 16);
    qa += __shfl_xor(qa, 32);
    if (lane < 8) sQ[wv][lane] = qa;
  }
  wave_lds_fence();   // f + sQ visible wave-wide

  // ---- score, mask, attention, Taylor coefs ----
#pragma unroll
  for (int i = 0; i < 8; ++i) Kp[i] += __shfl_xor(Kp[i], 1);
  float s = 0.0f;
#pragma unroll
  for (int i = 0; i < 8; ++i) s += fmaxf(sQ[wv][i] + Kp[i], 0.0f);
  s *= 0.125f;
  if (!mk) s = 0.0f;
  float d = s;
  d += __shfl_xor(d, 2);
  d += __shfl_xor(d, 4);
  d += __shfl_xor(d, 8);
  d += __shfl_xor(d, 16);
  d += __shfl_xor(d, 32);
  const float att = s / fmaxf(d, 1e-8f);
  if (h == 0) {
    float* wd = &sAtt[wv][n << 3];
    *(float4*)wd       = make_float4(att, att*uu.x, att*uu.y, att*uu.x*uu.x);
    *(float2*)(wd + 4) = make_float2(2.0f*att*uu.x*uu.y, att*uu.y*uu.y);
  }
  wave_lds_fence();   // sAtt visible wave-wide

  // ---- h_o[c,j] = sum_n coef_o(n) * f[n,c,j]   (lane = c*8+j) ----
  float hacc[6] = {0,0,0,0,0,0};
#pragma unroll 8
  for (int k = 0; k < 32; ++k) {
    const float fv = __uint_as_float(((unsigned int)sFw[k*66 + lane]) << 16);
    const float4 wA = *(const float4*)&sAtt[wv][k << 3];
    const float2 wB = *(const float2*)&sAtt[wv][(k << 3) + 4];
    hacc[0] += wA.x*fv; hacc[1] += wA.y*fv; hacc[2] += wA.z*fv;
    hacc[3] += wA.w*fv; hacc[4] += wB.x*fv; hacc[5] += wB.y*fv;
  }

  // ---- out[c,i] = sum_o sum_j WV_o[c,i,j] h_o[c,j] ----
  const int fc = lane >> 3;
  const int fj = lane & 7;
  float myout = 0.0f;
#pragma unroll
  for (int i = 0; i < 8; ++i) {
    const float* wvp = sW + 1088 + (fc*8 + i)*9 + fj;
    float p = wvp[0]*hacc[0] + wvp[576]*hacc[1] + wvp[1152]*hacc[2]
            + wvp[1728]*hacc[3] + wvp[2304]*hacc[4] + wvp[2880]*hacc[5];
    p += __shfl_xor(p, 1);
    p += __shfl_xor(p, 2);
    p += __shfl_xor(p, 4);
    if (fj == i) myout = p;
  }
  out[((size_t)v << 6) + lane] = myout;
}

extern "C" void kernel_launch(void* const* d_in, const int* in_sizes, int n_in,
                              void* d_out, int out_size, void* d_ws, size_t ws_size,
                              hipStream_t stream) {
  const float* x   = (const float*)d_in[0];
  const int*   nb  = (const int*)d_in[1];
  const void*  msk = d_in[2];
  const float* ptm = (const float*)d_in[3];
  const float* rpu = (const float*)d_in[4];
  const float* rb  = (const float*)d_in[5];
  const float* qc  = (const float*)d_in[6];
  const float* kc  = (const float*)d_in[7];
  const float* vb0 = (const float*)d_in[8];
  const float* vb1 = (const float*)d_in[9];
  const float* vb2 = (const float*)d_in[10];
  const float* vp0 = (const float*)d_in[11];
  const float* vp1 = (const float*)d_in[12];
  const float* vp2 = (const float*)d_in[13];
  (void)in_sizes; (void)n_in; (void)out_size; (void)d_ws; (void)ws_size;

  ge_attn<<<NVERT / 4, 256, 0, stream>>>(x, nb, msk, ptm, rpu, rb, qc, kc,
                                         vb0, vb1, vb2, vp0, vp1, vp2,
                                         (float*)d_out);
}

// Round 8
// 316.994 us; speedup vs baseline: 1.5062x; 1.5062x over previous
//
#include <hip/hip_runtime.h>

#define NVERT 40000

// R7 structure: lane = n8*8 + c (n8 = neighbor-in-group 0..7, c = channel 0..7),
// 4 passes over neighbor groups. All per-vertex state lives in registers
// (f[4][8], Q[8], scores); cross-lane sums use shfl_xor butterflies:
// bits 0-2 (c) for channel reductions, bits 3-5 (n8) for neighbor reductions.
// LDS holds only precomputed W mats (17.9 KB): WQ/WK i-major stride-8 rows
// (aligned float4, 8-way broadcast + 2-way bank alias = free), WV stride-9
// rows (conflict-free scalar reads at lane*9). One __syncthreads total; no
// fences; no LDS writes afterward. All math f32.
// Register budget ~95 true need -> __launch_bounds__(256,2) caps at 128
// without spilling (R6 spilled because the old layout truly needed ~150).

__global__ __launch_bounds__(256, 2)
void ge_attn(const float* __restrict__ x,
             const int* __restrict__ nbr,
             const void* __restrict__ maskp,
             const float* __restrict__ ptm,
             const float* __restrict__ rpu,
             const float* __restrict__ rbasis,
             const float* __restrict__ qcoef,
             const float* __restrict__ kcoef,
             const float* __restrict__ vb0,
             const float* __restrict__ vb1,
             const float* __restrict__ vb2,
             const float* __restrict__ vp0,
             const float* __restrict__ vp1,
             const float* __restrict__ vp2,
             float* __restrict__ out)
{
  __shared__ float sW[4480];   // WQ[i][c][8]@0 | WK@512 | WV_o rows stride9 @1024+o*576
  __shared__ int sFlagB, sFlagF;

  const int tid = threadIdx.x;
  if (tid == 0) { sFlagB = 0; sFlagF = 0; }
  __syncthreads();

  // ---- mask dtype probe (bool bytes vs int32 vs float32), deterministic ----
  {
    const unsigned int* mw = (const unsigned int*)maskp;
    int b0 = 0, b1 = 0;
#pragma unroll
    for (int t = 0; t < 8; ++t) {
      const unsigned int w = mw[tid + (t << 8)];
      b1 |= (w == 0x3F800000u) ? 1 : 0;
      b0 |= (w > 1u && w != 0x3F800000u) ? 1 : 0;
    }
    if (b0) sFlagB = 1;   // packed bool bytes
    if (b1) sFlagF = 1;   // float 1.0f pattern
  }

  // ---- per-block W precompute into LDS (new layouts) ----
  for (int r = tid; r < 512; r += 256) {
    const int m = r >> 6;
    const int cc = (r >> 3) & 7;
    const int ii = r & 7;
    const float* par; const float* bas; int ospan, oo;
    switch (m) {
      case 0:  par = qcoef; bas = rbasis; ospan = 1; oo = 0; break;
      case 1:  par = kcoef; bas = rbasis; ospan = 1; oo = 0; break;
      case 2:  par = vp0;   bas = vb0;    ospan = 1; oo = 0; break;
      case 3:  par = vp1;   bas = vb1;    ospan = 2; oo = 0; break;
      case 4:  par = vp1;   bas = vb1;    ospan = 2; oo = 1; break;
      case 5:  par = vp2;   bas = vb2;    ospan = 3; oo = 0; break;
      case 6:  par = vp2;   bas = vb2;    ospan = 3; oo = 1; break;
      default: par = vp2;   bas = vb2;    ospan = 3; oo = 2; break;
    }
    float acc[8] = {0,0,0,0,0,0,0,0};
#pragma unroll
    for (int b = 0; b < 8; ++b) {
      const float cf = par[cc*8 + b];
      const float* row = bas + (((b*ospan + oo)*8 + ii) << 3);
#pragma unroll
      for (int j = 0; j < 8; ++j) acc[j] += cf * row[j];
    }
    float* dst;
    if (m == 0)      dst = sW + (((ii << 3) + cc) << 3);
    else if (m == 1) dst = sW + 512 + (((ii << 3) + cc) << 3);
    else             dst = sW + 1024 + (m - 2)*576 + ((ii << 3) + cc)*9;
#pragma unroll
    for (int j = 0; j < 8; ++j) dst[j] = acc[j];
  }
  __syncthreads();   // only block-wide barrier; sW read-only below

  const int mode = sFlagB ? 1 : (sFlagF ? 2 : 0);

  const int wv   = tid >> 6;
  const int lane = tid & 63;
  const int n8   = lane >> 3;   // neighbor within group
  const int c    = lane & 7;    // channel
  const int v    = (blockIdx.x << 2) + wv;   // grid is exactly NVERT/4

  // ---- early independent loads (nbr / rpu / mask for all 4 passes) ----
  int   nbv[4];
  float u0[4], u1[4];
  int   mkb[4];
#pragma unroll
  for (int p = 0; p < 4; ++p) {
    const int mi = (v << 5) + (p << 3) + n8;
    nbv[p] = nbr[mi];
    const float2 uu = *(const float2*)(rpu + ((size_t)mi << 1));
    u0[p] = uu.x; u1[p] = uu.y;
    int mk;
    if (mode == 1)      mk = ((const unsigned char*)maskp)[mi] != 0;
    else if (mode == 2) mk = ((((const unsigned int*)maskp)[mi]) & 0x7FFFFFFFu) != 0u;
    else                mk = ((const int*)maskp)[mi] != 0;
    mkb[p] = mk;
  }

  // ---- Q[i] = sum_c sum_j WQ[c,i,j] x[v,c,j]  (c-butterfly) ----
  float Q[8];
  {
    const float* xq = x + ((size_t)v << 6) + (c << 3);
    const float4 qa = *(const float4*)xq;
    const float4 qb = *(const float4*)(xq + 4);
#pragma unroll
    for (int i = 0; i < 8; ++i) {
      const float* wq = &sW[((i << 3) + c) << 3];
      const float4 wa = *(const float4*)wq;
      const float4 wb = *(const float4*)(wq + 4);
      float q = wa.x*qa.x + wa.y*qa.y + wa.z*qa.z + wa.w*qa.w
              + wb.x*qb.x + wb.y*qb.y + wb.z*qb.z + wb.w*qb.w;
      q += __shfl_xor(q, 1);
      q += __shfl_xor(q, 2);
      q += __shfl_xor(q, 4);
      Q[i] = q;
    }
  }

  // ---- passes: transport f, K, score ----
  float f[4][8];
  float s[4];
#pragma unroll
  for (int p = 0; p < 4; ++p) {
    const int n = (p << 3) + n8;
    const float* xb = x + ((size_t)nbv[p] << 6) + (c << 3);
    const float4 xa = *(const float4*)xb;
    const float4 xc = *(const float4*)(xb + 4);
    const float* pr = ptm + ((size_t)((v << 5) + n) << 6);   // 8x8 row-major
#pragma unroll
    for (int i = 0; i < 8; ++i) {
      const float4 pa = *(const float4*)(pr + (i << 3));
      const float4 pb = *(const float4*)(pr + (i << 3) + 4);
      f[p][i] = pa.x*xa.x + pa.y*xa.y + pa.z*xa.z + pa.w*xa.w
              + pb.x*xc.x + pb.y*xc.y + pb.z*xc.z + pb.w*xc.w;
    }
    float sc = 0.0f;
#pragma unroll
    for (int i = 0; i < 8; ++i) {
      const float* wk = &sW[512 + (((i << 3) + c) << 3)];
      const float4 wa = *(const float4*)wk;
      const float4 wb = *(const float4*)(wk + 4);
      float k = wa.x*f[p][0] + wa.y*f[p][1] + wa.z*f[p][2] + wa.w*f[p][3]
              + wb.x*f[p][4] + wb.y*f[p][5] + wb.z*f[p][6] + wb.w*f[p][7];
      k += __shfl_xor(k, 1);
      k += __shfl_xor(k, 2);
      k += __shfl_xor(k, 4);
      sc += fmaxf(Q[i] + k, 0.0f);
    }
    s[p] = mkb[p] ? sc * 0.125f : 0.0f;
  }

  // ---- attention: denom over all 32 neighbors (n8-butterfly) ----
  float dt = s[0] + s[1] + s[2] + s[3];
  dt += __shfl_xor(dt, 8);
  dt += __shfl_xor(dt, 16);
  dt += __shfl_xor(dt, 32);
  const float rden = 1.0f / fmaxf(dt, 1e-8f);
  float a0[4], a1[4], a2[4];
#pragma unroll
  for (int p = 0; p < 4; ++p) {
    const float a = s[p] * rden;
    a0[p] = a;            // att
    a1[p] = a * u0[p];    // att*u0
    a2[p] = a * u1[p];    // att*u1
  }

  // ---- value path: lane computes out[c][i=n8] ----
  float outv = 0.0f;
#pragma unroll
  for (int o = 0; o < 6; ++o) {
    float t[8] = {0,0,0,0,0,0,0,0};
#pragma unroll
    for (int p = 0; p < 4; ++p) {
      float cf;
      if (o == 0)      cf = a0[p];
      else if (o == 1) cf = a1[p];
      else if (o == 2) cf = a2[p];
      else if (o == 3) cf = a1[p] * u0[p];           // att*u0^2
      else if (o == 4) cf = 2.0f * a1[p] * u1[p];    // 2*att*u0*u1
      else             cf = a2[p] * u1[p];           // att*u1^2
#pragma unroll
      for (int j = 0; j < 8; ++j) t[j] += cf * f[p][j];
    }
#pragma unroll
    for (int j = 0; j < 8; ++j) {
      t[j] += __shfl_xor(t[j], 8);
      t[j] += __shfl_xor(t[j], 16);
      t[j] += __shfl_xor(t[j], 32);
    }
    const float* wvp = &sW[1024 + o*576 + lane*9];   // WV_o[c][i=n8][:]
    outv += wvp[0]*t[0] + wvp[1]*t[1] + wvp[2]*t[2] + wvp[3]*t[3]
          + wvp[4]*t[4] + wvp[5]*t[5] + wvp[6]*t[6] + wvp[7]*t[7];
  }
  out[((size_t)v << 6) + (c << 3) + n8] = outv;
}

extern "C" void kernel_launch(void* const* d_in, const int* in_sizes, int n_in,
                              void* d_out, int out_size, void* d_ws, size_t ws_size,
                              hipStream_t stream) {
  const float* x   = (const float*)d_in[0];
  const int*   nb  = (const int*)d_in[1];
  const void*  msk = d_in[2];
  const float* ptm = (const float*)d_in[3];
  const float* rpu = (const float*)d_in[4];
  const float* rb  = (const float*)d_in[5];
  const float* qc  = (const float*)d_in[6];
  const float* kc  = (const float*)d_in[7];
  const float* vb0 = (const float*)d_in[8];
  const float* vb1 = (const float*)d_in[9];
  const float* vb2 = (const float*)d_in[10];
  const float* vp0 = (const float*)d_in[11];
  const float* vp1 = (const float*)d_in[12];
  const float* vp2 = (const float*)d_in[13];
  (void)in_sizes; (void)n_in; (void)out_size; (void)d_ws; (void)ws_size;

  ge_attn<<<NVERT / 4, 256, 0, stream>>>(x, nb, msk, ptm, rpu, rb, qc, kc,
                                         vb0, vb1, vb2, vp0, vp1, vp2,
                                         (float*)d_out);
}

// Round 9
// 307.466 us; speedup vs baseline: 1.5529x; 1.0310x over previous
//
#include <hip/hip_runtime.h>

#define NVERT 40000

// R9 = R8 lane layout (lane = n8*8 + c, 4 neighbor-group passes) with the ptm
// load pipeline moved to LDS to cut register pressure:
//  - ptm[v] staged per-wave into LDS as bf16 (4KB/wave), XOR-swizzled units
//    (i^n8) so transport ds_read_b128 is bank-conflict-free (c-lanes broadcast).
//  - transport reads rows from LDS (short-latency, shallow pipeline) instead of
//    keeping 16 float4 HBM loads in flight (the 64-VGPR culprit in R8's spill).
//  - sched_barrier(ALU-only may cross) at pass boundaries stops cross-pass
//    VMEM/DS hoisting; next pass's x-gather is software-pipelined by hand.
// True need ~110 VGPR -> __launch_bounds__(256,2) caps at 128 with NO spill,
// 4 waves/SIMD. LDS = sW 17.9KB + 4x4KB sF = 34.3KB -> 4 blocks/CU.

__device__ __forceinline__ void wave_lds_fence() {
  asm volatile("s_waitcnt lgkmcnt(0)" ::: "memory");
}
__device__ __forceinline__ void pass_sched_fence() {
  __builtin_amdgcn_sched_barrier(0x7);   // ALU/VALU/SALU may cross; VMEM+DS may not
}

__device__ __forceinline__ unsigned int pack_bf2(float a, float b) {
  return ((__float_as_uint(a) + 0x8000u) >> 16) |
         ((__float_as_uint(b) + 0x8000u) & 0xFFFF0000u);
}
__device__ __forceinline__ float bf_lo(unsigned int u) { return __uint_as_float(u << 16); }
__device__ __forceinline__ float bf_hi(unsigned int u) { return __uint_as_float(u & 0xFFFF0000u); }

__global__ __launch_bounds__(256, 2)
void ge_attn(const float* __restrict__ x,
             const int* __restrict__ nbr,
             const void* __restrict__ maskp,
             const float* __restrict__ ptm,
             const float* __restrict__ rpu,
             const float* __restrict__ rbasis,
             const float* __restrict__ qcoef,
             const float* __restrict__ kcoef,
             const float* __restrict__ vb0,
             const float* __restrict__ vb1,
             const float* __restrict__ vb2,
             const float* __restrict__ vp0,
             const float* __restrict__ vp1,
             const float* __restrict__ vp2,
             float* __restrict__ out)
{
  __shared__ float sW[4480];               // WQ@0 | WK@512 | WV_o stride9 @1024+o*576
  __shared__ unsigned short sF[4][2048];   // per-wave ptm bf16: 32n x 8 units x 16B, unit=(n*8)|(i^(n&7))
  __shared__ int sFlagB, sFlagF;

  const int tid = threadIdx.x;
  if (tid == 0) { sFlagB = 0; sFlagF = 0; }
  __syncthreads();

  // ---- mask dtype probe (bool bytes vs int32 vs float32), deterministic ----
  {
    const unsigned int* mw = (const unsigned int*)maskp;
    int b0 = 0, b1 = 0;
#pragma unroll
    for (int t = 0; t < 8; ++t) {
      const unsigned int w = mw[tid + (t << 8)];
      b1 |= (w == 0x3F800000u) ? 1 : 0;
      b0 |= (w > 1u && w != 0x3F800000u) ? 1 : 0;
    }
    if (b0) sFlagB = 1;   // packed bool bytes
    if (b1) sFlagF = 1;   // float 1.0f pattern
  }

  // ---- per-block W precompute into LDS ----
  for (int r = tid; r < 512; r += 256) {
    const int m = r >> 6;
    const int cc = (r >> 3) & 7;
    const int ii = r & 7;
    const float* par; const float* bas; int ospan, oo;
    switch (m) {
      case 0:  par = qcoef; bas = rbasis; ospan = 1; oo = 0; break;
      case 1:  par = kcoef; bas = rbasis; ospan = 1; oo = 0; break;
      case 2:  par = vp0;   bas = vb0;    ospan = 1; oo = 0; break;
      case 3:  par = vp1;   bas = vb1;    ospan = 2; oo = 0; break;
      case 4:  par = vp1;   bas = vb1;    ospan = 2; oo = 1; break;
      case 5:  par = vp2;   bas = vb2;    ospan = 3; oo = 0; break;
      case 6:  par = vp2;   bas = vb2;    ospan = 3; oo = 1; break;
      default: par = vp2;   bas = vb2;    ospan = 3; oo = 2; break;
    }
    float acc[8] = {0,0,0,0,0,0,0,0};
#pragma unroll
    for (int b = 0; b < 8; ++b) {
      const float cf = par[cc*8 + b];
      const float* row = bas + (((b*ospan + oo)*8 + ii) << 3);
#pragma unroll
      for (int j = 0; j < 8; ++j) acc[j] += cf * row[j];
    }
    float* dst;
    if (m == 0)      dst = sW + (((ii << 3) + cc) << 3);
    else if (m == 1) dst = sW + 512 + (((ii << 3) + cc) << 3);
    else             dst = sW + 1024 + (m - 2)*576 + ((ii << 3) + cc)*9;
#pragma unroll
    for (int j = 0; j < 8; ++j) dst[j] = acc[j];
  }
  __syncthreads();   // only block-wide barrier

  const int mode = sFlagB ? 1 : (sFlagF ? 2 : 0);

  const int wv   = tid >> 6;
  const int lane = tid & 63;
  const int n8   = lane >> 3;   // neighbor within group
  const int c    = lane & 7;    // channel
  const int v    = (blockIdx.x << 2) + wv;   // grid is exactly NVERT/4
  unsigned short* sFw = sF[wv];

  // ---- early independent loads (nbr / rpu / mask for all 4 passes) ----
  int   nbv[4];
  float u0[4], u1[4];
  int   mkb[4];
#pragma unroll
  for (int p = 0; p < 4; ++p) {
    const int mi = (v << 5) + (p << 3) + n8;
    nbv[p] = nbr[mi];
    const float2 uu = *(const float2*)(rpu + ((size_t)mi << 1));
    u0[p] = uu.x; u1[p] = uu.y;
    int mk;
    if (mode == 1)      mk = ((const unsigned char*)maskp)[mi] != 0;
    else if (mode == 2) mk = ((((const unsigned int*)maskp)[mi]) & 0x7FFFFFFFu) != 0u;
    else                mk = ((const int*)maskp)[mi] != 0;
    mkb[p] = mk;
  }

  // ---- stage ptm[v] into LDS as bf16, swizzled units (coalesced 1KB/instr) ----
  {
    const float4* p4 = (const float4*)(ptm + (size_t)v * 2048);
#pragma unroll
    for (int t = 0; t < 8; ++t) {
      const int g = lane + (t << 6);          // 0..511 float4s
      const float4 val = p4[g];
      const int n  = g >> 4;
      const int ii = (g >> 1) & 7;
      const int hh = g & 1;
      const int unit = (n << 3) | (ii ^ (n & 7));
      *(uint2*)&sFw[(unit << 3) + (hh << 2)] =
          make_uint2(pack_bf2(val.x, val.y), pack_bf2(val.z, val.w));
    }
  }

  // ---- Q[i] = sum_c sum_j WQ[c,i,j] x[v,c,j]  (c-butterfly) ----
  float Q[8];
  {
    const float* xq = x + ((size_t)v << 6) + (c << 3);
    const float4 qa = *(const float4*)xq;
    const float4 qb = *(const float4*)(xq + 4);
#pragma unroll
    for (int i = 0; i < 8; ++i) {
      const float* wq = &sW[((i << 3) + c) << 3];
      const float4 wa = *(const float4*)wq;
      const float4 wb = *(const float4*)(wq + 4);
      float q = wa.x*qa.x + wa.y*qa.y + wa.z*qa.z + wa.w*qa.w
              + wb.x*qb.x + wb.y*qb.y + wb.z*qb.z + wb.w*qb.w;
      q += __shfl_xor(q, 1);
      q += __shfl_xor(q, 2);
      q += __shfl_xor(q, 4);
      Q[i] = q;
    }
  }

  wave_lds_fence();   // own-wave staging complete before transport reads

  // ---- passes: transport f (ptm rows from LDS), K, score ----
  float f[4][8];
  float s[4];
  const float* xb0 = x + ((size_t)nbv[0] << 6) + (c << 3);
  float4 xa = *(const float4*)xb0;
  float4 xc = *(const float4*)(xb0 + 4);
#pragma unroll
  for (int p = 0; p < 4; ++p) {
    // software-pipelined next x-gather (issued under this pass's compute)
    float4 xan, xcn;
    if (p < 3) {
      const float* xbn = x + ((size_t)nbv[p + 1] << 6) + (c << 3);
      xan = *(const float4*)xbn;
      xcn = *(const float4*)(xbn + 4);
    }
#pragma unroll
    for (int i = 0; i < 8; ++i) {
      const int unit = (((p << 3) + n8) << 3) | (i ^ n8);
      const uint4 r = *(const uint4*)&sFw[unit << 3];
      const float p0 = bf_lo(r.x), p1 = bf_hi(r.x);
      const float p2 = bf_lo(r.y), p3 = bf_hi(r.y);
      const float p4v = bf_lo(r.z), p5 = bf_hi(r.z);
      const float p6 = bf_lo(r.w), p7 = bf_hi(r.w);
      f[p][i] = p0*xa.x + p1*xa.y + p2*xa.z + p3*xa.w
              + p4v*xc.x + p5*xc.y + p6*xc.z + p7*xc.w;
    }
    float sc = 0.0f;
#pragma unroll
    for (int i = 0; i < 8; ++i) {
      const float* wk = &sW[512 + (((i << 3) + c) << 3)];
      const float4 wa = *(const float4*)wk;
      const float4 wb = *(const float4*)(wk + 4);
      float k = wa.x*f[p][0] + wa.y*f[p][1] + wa.z*f[p][2] + wa.w*f[p][3]
              + wb.x*f[p][4] + wb.y*f[p][5] + wb.z*f[p][6] + wb.w*f[p][7];
      k += __shfl_xor(k, 1);
      k += __shfl_xor(k, 2);
      k += __shfl_xor(k, 4);
      sc += fmaxf(Q[i] + k, 0.0f);
    }
    s[p] = mkb[p] ? sc * 0.125f : 0.0f;
    if (p < 3) { xa = xan; xc = xcn; }
    pass_sched_fence();   // VMEM/DS may not cross pass boundary
  }

  // ---- attention: denom over all 32 neighbors (n8-butterfly) ----
  float dt = s[0] + s[1] + s[2] + s[3];
  dt += __shfl_xor(dt, 8);
  dt += __shfl_xor(dt, 16);
  dt += __shfl_xor(dt, 32);
  const float rden = 1.0f / fmaxf(dt, 1e-8f);
  float a0[4], a1[4], a2[4];
#pragma unroll
  for (int p = 0; p < 4; ++p) {
    const float a = s[p] * rden;
    a0[p] = a;            // att
    a1[p] = a * u0[p];    // att*u0
    a2[p] = a * u1[p];    // att*u1
  }

  // ---- value path: lane computes out[c][i=n8] ----
  float outv = 0.0f;
#pragma unroll
  for (int o = 0; o < 6; ++o) {
    float t[8] = {0,0,0,0,0,0,0,0};
#pragma unroll
    for (int p = 0; p < 4; ++p) {
      float cf;
      if (o == 0)      cf = a0[p];
      else if (o == 1) cf = a1[p];
      else if (o == 2) cf = a2[p];
      else if (o == 3) cf = a1[p] * u0[p];           // att*u0^2
      else if (o == 4) cf = 2.0f * a1[p] * u1[p];    // 2*att*u0*u1
      else             cf = a2[p] * u1[p];           // att*u1^2
#pragma unroll
      for (int j = 0; j < 8; ++j) t[j] += cf * f[p][j];
    }
#pragma unroll
    for (int j = 0; j < 8; ++j) {
      t[j] += __shfl_xor(t[j], 8);
      t[j] += __shfl_xor(t[j], 16);
      t[j] += __shfl_xor(t[j], 32);
    }
    const float* wvp = &sW[1024 + o*576 + lane*9];   // WV_o[c][i=n8][:]
    outv += wvp[0]*t[0] + wvp[1]*t[1] + wvp[2]*t[2] + wvp[3]*t[3]
          + wvp[4]*t[4] + wvp[5]*t[5] + wvp[6]*t[6] + wvp[7]*t[7];
  }
  out[((size_t)v << 6) + (c << 3) + n8] = outv;
}

extern "C" void kernel_launch(void* const* d_in, const int* in_sizes, int n_in,
                              void* d_out, int out_size, void* d_ws, size_t ws_size,
                              hipStream_t stream) {
  const float* x   = (const float*)d_in[0];
  const int*   nb  = (const int*)d_in[1];
  const void*  msk = d_in[2];
  const float* ptm = (const float*)d_in[3];
  const float* rpu = (const float*)d_in[4];
  const float* rb  = (const float*)d_in[5];
  const float* qc  = (const float*)d_in[6];
  const float* kc  = (const float*)d_in[7];
  const float* vb0 = (const float*)d_in[8];
  const float* vb1 = (const float*)d_in[9];
  const float* vb2 = (const float*)d_in[10];
  const float* vp0 = (const float*)d_in[11];
  const float* vp1 = (const float*)d_in[12];
  const float* vp2 = (const float*)d_in[13];
  (void)in_sizes; (void)n_in; (void)out_size; (void)d_ws; (void)ws_size;

  ge_attn<<<NVERT / 4, 256, 0, stream>>>(x, nb, msk, ptm, rpu, rb, qc, kc,
                                         vb0, vb1, vb2, vp0, vp1, vp2,
                                         (float*)d_out);
}

// Round 10
// 284.326 us; speedup vs baseline: 1.6793x; 1.0814x over previous
//
#include <hip/hip_runtime.h>

#define NVERT 40000

// R10 = R9 (lane = n8*8+c, 4 passes, ptm staged to LDS bf16 swizzled) plus:
//  - f spilled to LDS (bf16) over the consumed ptm row instead of scratch:
//    pass p writes f at row (p*8+n8), unit (c^n8); value path re-reads it in
//    two 3-coef halves (24 acc regs live). Frees 32 VGPRs.
//  - Q/K channel reductions as reduce-scatter (lane c keeps index c only):
//    7 sel+shfl+add triplets instead of 24-shfl allreduce; Q[8] -> Q1 scalar.
//  - mask bits packed into one int.
// True need ~105 VGPR < 128 cap of __launch_bounds__(256,2): NO spill,
// 4 waves/SIMD (max for the 128-VGPR class per occupancy ladder R5/R8/R9).
// LDS 34.4KB -> 4 blocks/CU.

__device__ __forceinline__ void wave_lds_fence() {
  asm volatile("s_waitcnt lgkmcnt(0)" ::: "memory");
}
__device__ __forceinline__ void pass_sched_fence() {
  __builtin_amdgcn_sched_barrier(0x7);   // ALU may cross; VMEM/DS may not
}

__device__ __forceinline__ unsigned int pack_bf2(float a, float b) {
  return ((__float_as_uint(a) + 0x8000u) >> 16) |
         ((__float_as_uint(b) + 0x8000u) & 0xFFFF0000u);
}
__device__ __forceinline__ float bf_lo(unsigned int u) { return __uint_as_float(u << 16); }
__device__ __forceinline__ float bf_hi(unsigned int u) { return __uint_as_float(u & 0xFFFF0000u); }

// reduce-scatter of 8 per-lane partials over c-lanes (xor 1,2,4):
// lane with octet-index c returns sum over octet of v[c].
__device__ __forceinline__ float rs8(const float v[8], int c) {
  float snd, kp, s0, s1, s2, s3, t0, t1;
  snd = (c & 1) ? v[0] : v[1]; kp = (c & 1) ? v[1] : v[0]; s0 = kp + __shfl_xor(snd, 1);
  snd = (c & 1) ? v[2] : v[3]; kp = (c & 1) ? v[3] : v[2]; s1 = kp + __shfl_xor(snd, 1);
  snd = (c & 1) ? v[4] : v[5]; kp = (c & 1) ? v[5] : v[4]; s2 = kp + __shfl_xor(snd, 1);
  snd = (c & 1) ? v[6] : v[7]; kp = (c & 1) ? v[7] : v[6]; s3 = kp + __shfl_xor(snd, 1);
  snd = (c & 2) ? s0 : s1;     kp = (c & 2) ? s1 : s0;     t0 = kp + __shfl_xor(snd, 2);
  snd = (c & 2) ? s2 : s3;     kp = (c & 2) ? s3 : s2;     t1 = kp + __shfl_xor(snd, 2);
  snd = (c & 4) ? t0 : t1;     kp = (c & 4) ? t1 : t0;     return kp + __shfl_xor(snd, 4);
}

__global__ __launch_bounds__(256, 2)
void ge_attn(const float* __restrict__ x,
             const int* __restrict__ nbr,
             const void* __restrict__ maskp,
             const float* __restrict__ ptm,
             const float* __restrict__ rpu,
             const float* __restrict__ rbasis,
             const float* __restrict__ qcoef,
             const float* __restrict__ kcoef,
             const float* __restrict__ vb0,
             const float* __restrict__ vb1,
             const float* __restrict__ vb2,
             const float* __restrict__ vp0,
             const float* __restrict__ vp1,
             const float* __restrict__ vp2,
             float* __restrict__ out)
{
  __shared__ float sW[4480];               // WQ@0 | WK@512 | WV_o stride9 @1024+o*576
  __shared__ unsigned short sF[4][2048];   // per-wave: ptm bf16, rows of 8 16B units
  __shared__ int sFlagB, sFlagF;

  const int tid = threadIdx.x;
  if (tid == 0) { sFlagB = 0; sFlagF = 0; }
  __syncthreads();

  // ---- mask dtype probe (bool bytes vs int32 vs float32), deterministic ----
  {
    const unsigned int* mw = (const unsigned int*)maskp;
    int b0 = 0, b1 = 0;
#pragma unroll
    for (int t = 0; t < 8; ++t) {
      const unsigned int w = mw[tid + (t << 8)];
      b1 |= (w == 0x3F800000u) ? 1 : 0;
      b0 |= (w > 1u && w != 0x3F800000u) ? 1 : 0;
    }
    if (b0) sFlagB = 1;
    if (b1) sFlagF = 1;
  }

  // ---- per-block W precompute into LDS ----
  for (int r = tid; r < 512; r += 256) {
    const int m = r >> 6;
    const int cc = (r >> 3) & 7;
    const int ii = r & 7;
    const float* par; const float* bas; int ospan, oo;
    switch (m) {
      case 0:  par = qcoef; bas = rbasis; ospan = 1; oo = 0; break;
      case 1:  par = kcoef; bas = rbasis; ospan = 1; oo = 0; break;
      case 2:  par = vp0;   bas = vb0;    ospan = 1; oo = 0; break;
      case 3:  par = vp1;   bas = vb1;    ospan = 2; oo = 0; break;
      case 4:  par = vp1;   bas = vb1;    ospan = 2; oo = 1; break;
      case 5:  par = vp2;   bas = vb2;    ospan = 3; oo = 0; break;
      case 6:  par = vp2;   bas = vb2;    ospan = 3; oo = 1; break;
      default: par = vp2;   bas = vb2;    ospan = 3; oo = 2; break;
    }
    float acc[8] = {0,0,0,0,0,0,0,0};
#pragma unroll
    for (int b = 0; b < 8; ++b) {
      const float cf = par[cc*8 + b];
      const float* row = bas + (((b*ospan + oo)*8 + ii) << 3);
#pragma unroll
      for (int j = 0; j < 8; ++j) acc[j] += cf * row[j];
    }
    float* dst;
    if (m == 0)      dst = sW + (((ii << 3) + cc) << 3);
    else if (m == 1) dst = sW + 512 + (((ii << 3) + cc) << 3);
    else             dst = sW + 1024 + (m - 2)*576 + ((ii << 3) + cc)*9;
#pragma unroll
    for (int j = 0; j < 8; ++j) dst[j] = acc[j];
  }
  __syncthreads();   // only block-wide barrier

  const int mode = sFlagB ? 1 : (sFlagF ? 2 : 0);

  const int wv   = tid >> 6;
  const int lane = tid & 63;
  const int n8   = lane >> 3;
  const int c    = lane & 7;
  const int v    = (blockIdx.x << 2) + wv;
  unsigned short* sFw = sF[wv];

  // ---- early independent loads ----
  int   nbv[4];
  float u0[4], u1[4];
  int   mkbits = 0;
#pragma unroll
  for (int p = 0; p < 4; ++p) {
    const int mi = (v << 5) + (p << 3) + n8;
    nbv[p] = nbr[mi];
    const float2 uu = *(const float2*)(rpu + ((size_t)mi << 1));
    u0[p] = uu.x; u1[p] = uu.y;
    int mk;
    if (mode == 1)      mk = ((const unsigned char*)maskp)[mi] != 0;
    else if (mode == 2) mk = ((((const unsigned int*)maskp)[mi]) & 0x7FFFFFFFu) != 0u;
    else                mk = ((const int*)maskp)[mi] != 0;
    mkbits |= (mk << p);
  }

  // ---- stage ptm[v] into LDS as bf16, swizzled units (unit = i^n8) ----
  {
    const float4* p4 = (const float4*)(ptm + (size_t)v * 2048);
#pragma unroll
    for (int t = 0; t < 8; ++t) {
      const int g = lane + (t << 6);
      const float4 val = p4[g];
      const int n  = g >> 4;
      const int ii = (g >> 1) & 7;
      const int hh = g & 1;
      const int unit = (n << 3) | (ii ^ (n & 7));
      *(uint2*)&sFw[(unit << 3) + (hh << 2)] =
          make_uint2(pack_bf2(val.x, val.y), pack_bf2(val.z, val.w));
    }
  }

  // ---- Q via reduce-scatter: lane ends with Q1 = Q[c] ----
  float Q1;
  {
    const float* xq = x + ((size_t)v << 6) + (c << 3);
    const float4 qa = *(const float4*)xq;
    const float4 qb = *(const float4*)(xq + 4);
    float qp[8];
#pragma unroll
    for (int i = 0; i < 8; ++i) {
      const float* wq = &sW[((i << 3) + c) << 3];
      const float4 wa = *(const float4*)wq;
      const float4 wb = *(const float4*)(wq + 4);
      qp[i] = wa.x*qa.x + wa.y*qa.y + wa.z*qa.z + wa.w*qa.w
            + wb.x*qb.x + wb.y*qb.y + wb.z*qb.z + wb.w*qb.w;
    }
    Q1 = rs8(qp, c);
  }

  wave_lds_fence();   // staging complete before transport reads

  // ---- passes: transport f (LDS), K reduce-scatter, score; f -> LDS bf16 ----
  float s[4];
  const float* xb0 = x + ((size_t)nbv[0] << 6) + (c << 3);
  float4 xa = *(const float4*)xb0;
  float4 xc = *(const float4*)(xb0 + 4);
#pragma unroll
  for (int p = 0; p < 4; ++p) {
    float4 xan, xcn;
    if (p < 3) {
      const float* xbn = x + ((size_t)nbv[p + 1] << 6) + (c << 3);
      xan = *(const float4*)xbn;
      xcn = *(const float4*)(xbn + 4);
    }
    const int rowb = ((p << 3) + n8) << 3;
    float fv[8];
#pragma unroll
    for (int i = 0; i < 8; ++i) {
      const uint4 r = *(const uint4*)&sFw[(rowb | (i ^ n8)) << 3];
      const float p0 = bf_lo(r.x), p1 = bf_hi(r.x);
      const float p2 = bf_lo(r.y), p3 = bf_hi(r.y);
      const float p4v = bf_lo(r.z), p5 = bf_hi(r.z);
      const float p6 = bf_lo(r.w), p7 = bf_hi(r.w);
      fv[i] = p0*xa.x + p1*xa.y + p2*xa.z + p3*xa.w
            + p4v*xc.x + p5*xc.y + p6*xc.z + p7*xc.w;
    }
    float kp[8];
#pragma unroll
    for (int i = 0; i < 8; ++i) {
      const float* wk = &sW[512 + (((i << 3) + c) << 3)];
      const float4 wa = *(const float4*)wk;
      const float4 wb = *(const float4*)(wk + 4);
      kp[i] = wa.x*fv[0] + wa.y*fv[1] + wa.z*fv[2] + wa.w*fv[3]
            + wb.x*fv[4] + wb.y*fv[5] + wb.z*fv[6] + wb.w*fv[7];
    }
    const float K1 = rs8(kp, c);
    float sc = fmaxf(Q1 + K1, 0.0f);
    sc += __shfl_xor(sc, 1);
    sc += __shfl_xor(sc, 2);
    sc += __shfl_xor(sc, 4);
    s[p] = ((mkbits >> p) & 1) ? sc * 0.125f : 0.0f;

    // write f (bf16) over the consumed ptm row, unit (c^n8)
    uint4 w;
    w.x = pack_bf2(fv[0], fv[1]);
    w.y = pack_bf2(fv[2], fv[3]);
    w.z = pack_bf2(fv[4], fv[5]);
    w.w = pack_bf2(fv[6], fv[7]);
    *(uint4*)&sFw[(rowb | (c ^ n8)) << 3] = w;

    if (p < 3) { xa = xan; xc = xcn; }
    pass_sched_fence();
  }

  // ---- attention normalization ----
  float dt = s[0] + s[1] + s[2] + s[3];
  dt += __shfl_xor(dt, 8);
  dt += __shfl_xor(dt, 16);
  dt += __shfl_xor(dt, 32);
  const float rden = 1.0f / fmaxf(dt, 1e-8f);
#pragma unroll
  for (int p = 0; p < 4; ++p) s[p] *= rden;   // s[p] = att

  wave_lds_fence();   // f writes visible before value re-reads

  // ---- value path in two 3-coef halves (24 acc regs live) ----
  float outv = 0.0f;
#pragma unroll
  for (int hlf = 0; hlf < 2; ++hlf) {
    float t0[8], t1[8], t2[8];
#pragma unroll
    for (int j = 0; j < 8; ++j) { t0[j] = 0.0f; t1[j] = 0.0f; t2[j] = 0.0f; }
#pragma unroll
    for (int p = 0; p < 4; ++p) {
      const uint4 r = *(const uint4*)&sFw[(((((p << 3) + n8) << 3)) | (c ^ n8)) << 3];
      float fj[8];
      fj[0] = bf_lo(r.x); fj[1] = bf_hi(r.x);
      fj[2] = bf_lo(r.y); fj[3] = bf_hi(r.y);
      fj[4] = bf_lo(r.z); fj[5] = bf_hi(r.z);
      fj[6] = bf_lo(r.w); fj[7] = bf_hi(r.w);
      const float a = s[p];
      float cf0, cf1, cf2;
      if (hlf == 0) { cf0 = a;                 cf1 = a * u0[p];              cf2 = a * u1[p]; }
      else          { cf0 = a * u0[p] * u0[p]; cf1 = 2.0f * a * u0[p] * u1[p]; cf2 = a * u1[p] * u1[p]; }
#pragma unroll
      for (int j = 0; j < 8; ++j) {
        t0[j] += cf0 * fj[j];
        t1[j] += cf1 * fj[j];
        t2[j] += cf2 * fj[j];
      }
    }
    // reduce over neighbors (n8-bits) and apply WV rows
#pragma unroll
    for (int j = 0; j < 8; ++j) {
      t0[j] += __shfl_xor(t0[j], 8);  t0[j] += __shfl_xor(t0[j], 16);  t0[j] += __shfl_xor(t0[j], 32);
      t1[j] += __shfl_xor(t1[j], 8);  t1[j] += __shfl_xor(t1[j], 16);  t1[j] += __shfl_xor(t1[j], 32);
      t2[j] += __shfl_xor(t2[j], 8);  t2[j] += __shfl_xor(t2[j], 16);  t2[j] += __shfl_xor(t2[j], 32);
    }
    const int ob = hlf * 3;
    const float* w0 = &sW[1024 + (ob + 0)*576 + lane*9];
    const float* w1 = &sW[1024 + (ob + 1)*576 + lane*9];
    const float* w2 = &sW[1024 + (ob + 2)*576 + lane*9];
#pragma unroll
    for (int j = 0; j < 8; ++j)
      outv += w0[j]*t0[j] + w1[j]*t1[j] + w2[j]*t2[j];
  }
  out[((size_t)v << 6) + (c << 3) + n8] = outv;
}

extern "C" void kernel_launch(void* const* d_in, const int* in_sizes, int n_in,
                              void* d_out, int out_size, void* d_ws, size_t ws_size,
                              hipStream_t stream) {
  const float* x   = (const float*)d_in[0];
  const int*   nb  = (const int*)d_in[1];
  const void*  msk = d_in[2];
  const float* ptm = (const float*)d_in[3];
  const float* rpu = (const float*)d_in[4];
  const float* rb  = (const float*)d_in[5];
  const float* qc  = (const float*)d_in[6];
  const float* kc  = (const float*)d_in[7];
  const float* vb0 = (const float*)d_in[8];
  const float* vb1 = (const float*)d_in[9];
  const float* vb2 = (const float*)d_in[10];
  const float* vp0 = (const float*)d_in[11];
  const float* vp1 = (const float*)d_in[12];
  const float* vp2 = (const float*)d_in[13];
  (void)in_sizes; (void)n_in; (void)out_size; (void)d_ws; (void)ws_size;

  ge_attn<<<NVERT / 4, 256, 0, stream>>>(x, nb, msk, ptm, rpu, rb, qc, kc,
                                         vb0, vb1, vb2, vp0, vp1, vp2,
                                         (float*)d_out);
}

// Round 12
// 186.217 us; speedup vs baseline: 2.5641x; 1.5269x over previous
//
#include <hip/hip_runtime.h>

#define NVERT 40000

// R12 = R11 with the WV indexing bug fixed: sW value-matrix rows are stored
// i-major (row = i*8 + c, stride 9), so WV_o[c][i][j=n8] sits at
// 1024 + o*576 + i*72 + c*9 + n8. R11 indexed rows c-major -> transposed fetch.
//  - value path via reduce-scatter (rs8n): 49 shuffles vs R10's 144.
//  - register diet: Q before ptm staging; u0/u1 in per-wave LDS sU.
// LDS: sW 17.9KB + sF 16KB + sU 1KB = 35.4KB -> 4 blocks/CU.

__device__ __forceinline__ void wave_lds_fence() {
  asm volatile("s_waitcnt lgkmcnt(0)" ::: "memory");
}
__device__ __forceinline__ void pass_sched_fence() {
  __builtin_amdgcn_sched_barrier(0x7);   // ALU may cross; VMEM/DS may not
}

__device__ __forceinline__ unsigned int pack_bf2(float a, float b) {
  return ((__float_as_uint(a) + 0x8000u) >> 16) |
         ((__float_as_uint(b) + 0x8000u) & 0xFFFF0000u);
}
__device__ __forceinline__ float bf_lo(unsigned int u) { return __uint_as_float(u << 16); }
__device__ __forceinline__ float bf_hi(unsigned int u) { return __uint_as_float(u & 0xFFFF0000u); }

// reduce-scatter over c-lanes (xor 1,2,4): lane with octet-index c gets sum of v[c].
__device__ __forceinline__ float rs8(const float v[8], int c) {
  float snd, kp, s0, s1, s2, s3, t0, t1;
  snd = (c & 1) ? v[0] : v[1]; kp = (c & 1) ? v[1] : v[0]; s0 = kp + __shfl_xor(snd, 1);
  snd = (c & 1) ? v[2] : v[3]; kp = (c & 1) ? v[3] : v[2]; s1 = kp + __shfl_xor(snd, 1);
  snd = (c & 1) ? v[4] : v[5]; kp = (c & 1) ? v[5] : v[4]; s2 = kp + __shfl_xor(snd, 1);
  snd = (c & 1) ? v[6] : v[7]; kp = (c & 1) ? v[7] : v[6]; s3 = kp + __shfl_xor(snd, 1);
  snd = (c & 2) ? s0 : s1;     kp = (c & 2) ? s1 : s0;     t0 = kp + __shfl_xor(snd, 2);
  snd = (c & 2) ? s2 : s3;     kp = (c & 2) ? s3 : s2;     t1 = kp + __shfl_xor(snd, 2);
  snd = (c & 4) ? t0 : t1;     kp = (c & 4) ? t1 : t0;     return kp + __shfl_xor(snd, 4);
}

// reduce-scatter over n8-lanes (xor 8,16,32): lane with group-index n8 gets sum of v[n8].
__device__ __forceinline__ float rs8n(const float v[8], int n8) {
  float snd, kp, s0, s1, s2, s3, t0, t1;
  snd = (n8 & 1) ? v[0] : v[1]; kp = (n8 & 1) ? v[1] : v[0]; s0 = kp + __shfl_xor(snd, 8);
  snd = (n8 & 1) ? v[2] : v[3]; kp = (n8 & 1) ? v[3] : v[2]; s1 = kp + __shfl_xor(snd, 8);
  snd = (n8 & 1) ? v[4] : v[5]; kp = (n8 & 1) ? v[5] : v[4]; s2 = kp + __shfl_xor(snd, 8);
  snd = (n8 & 1) ? v[6] : v[7]; kp = (n8 & 1) ? v[7] : v[6]; s3 = kp + __shfl_xor(snd, 8);
  snd = (n8 & 2) ? s0 : s1;     kp = (n8 & 2) ? s1 : s0;     t0 = kp + __shfl_xor(snd, 16);
  snd = (n8 & 2) ? s2 : s3;     kp = (n8 & 2) ? s3 : s2;     t1 = kp + __shfl_xor(snd, 16);
  snd = (n8 & 4) ? t0 : t1;     kp = (n8 & 4) ? t1 : t0;     return kp + __shfl_xor(snd, 32);
}

__global__ __launch_bounds__(256, 2)
void ge_attn(const float* __restrict__ x,
             const int* __restrict__ nbr,
             const void* __restrict__ maskp,
             const float* __restrict__ ptm,
             const float* __restrict__ rpu,
             const float* __restrict__ rbasis,
             const float* __restrict__ qcoef,
             const float* __restrict__ kcoef,
             const float* __restrict__ vb0,
             const float* __restrict__ vb1,
             const float* __restrict__ vb2,
             const float* __restrict__ vp0,
             const float* __restrict__ vp1,
             const float* __restrict__ vp2,
             float* __restrict__ out)
{
  __shared__ float sW[4480];               // WQ@0 | WK@512 | WV_o rows (i*8+c) stride9 @1024+o*576
  __shared__ unsigned short sF[4][2048];   // per-wave ptm/f bf16, rows of 8 16B units
  __shared__ float sU[4][64];              // per-wave u: (p*8+n8)*2 + {0,1}
  __shared__ int sFlagB, sFlagF;

  const int tid = threadIdx.x;
  if (tid == 0) { sFlagB = 0; sFlagF = 0; }
  __syncthreads();

  // ---- mask dtype probe (bool bytes vs int32 vs float32), deterministic ----
  {
    const unsigned int* mw = (const unsigned int*)maskp;
    int b0 = 0, b1 = 0;
#pragma unroll
    for (int t = 0; t < 8; ++t) {
      const unsigned int w = mw[tid + (t << 8)];
      b1 |= (w == 0x3F800000u) ? 1 : 0;
      b0 |= (w > 1u && w != 0x3F800000u) ? 1 : 0;
    }
    if (b0) sFlagB = 1;
    if (b1) sFlagF = 1;
  }

  // ---- per-block W precompute into LDS ----
  for (int r = tid; r < 512; r += 256) {
    const int m = r >> 6;
    const int cc = (r >> 3) & 7;
    const int ii = r & 7;
    const float* par; const float* bas; int ospan, oo;
    switch (m) {
      case 0:  par = qcoef; bas = rbasis; ospan = 1; oo = 0; break;
      case 1:  par = kcoef; bas = rbasis; ospan = 1; oo = 0; break;
      case 2:  par = vp0;   bas = vb0;    ospan = 1; oo = 0; break;
      case 3:  par = vp1;   bas = vb1;    ospan = 2; oo = 0; break;
      case 4:  par = vp1;   bas = vb1;    ospan = 2; oo = 1; break;
      case 5:  par = vp2;   bas = vb2;    ospan = 3; oo = 0; break;
      case 6:  par = vp2;   bas = vb2;    ospan = 3; oo = 1; break;
      default: par = vp2;   bas = vb2;    ospan = 3; oo = 2; break;
    }
    float acc[8] = {0,0,0,0,0,0,0,0};
#pragma unroll
    for (int b = 0; b < 8; ++b) {
      const float cf = par[cc*8 + b];
      const float* row = bas + (((b*ospan + oo)*8 + ii) << 3);
#pragma unroll
      for (int j = 0; j < 8; ++j) acc[j] += cf * row[j];
    }
    float* dst;
    if (m == 0)      dst = sW + (((ii << 3) + cc) << 3);
    else if (m == 1) dst = sW + 512 + (((ii << 3) + cc) << 3);
    else             dst = sW + 1024 + (m - 2)*576 + ((ii << 3) + cc)*9;
#pragma unroll
    for (int j = 0; j < 8; ++j) dst[j] = acc[j];
  }
  __syncthreads();   // only block-wide barrier

  const int mode = sFlagB ? 1 : (sFlagF ? 2 : 0);

  const int wv   = tid >> 6;
  const int lane = tid & 63;
  const int n8   = lane >> 3;
  const int c    = lane & 7;
  const int v    = (blockIdx.x << 2) + wv;
  unsigned short* sFw = sF[wv];
  float* sUw = sU[wv];

  // ---- early independent loads: nbr, mask (packed), u -> LDS ----
  int nbv[4];
  int mkbits = 0;
#pragma unroll
  for (int p = 0; p < 4; ++p) {
    const int mi = (v << 5) + (p << 3) + n8;
    nbv[p] = nbr[mi];
    int mk;
    if (mode == 1)      mk = ((const unsigned char*)maskp)[mi] != 0;
    else if (mode == 2) mk = ((((const unsigned int*)maskp)[mi]) & 0x7FFFFFFFu) != 0u;
    else                mk = ((const int*)maskp)[mi] != 0;
    mkbits |= (mk << p);
  }
  if (c < 4) {   // lane handles p=c: one float2 per (p,n8)
    const int mi = (v << 5) + (c << 3) + n8;
    const float2 uu = *(const float2*)(rpu + ((size_t)mi << 1));
    *(float2*)&sUw[((c << 3) + n8) << 1] = uu;
  }

  // ---- Q via reduce-scatter (before staging: de-overlap live ranges) ----
  float Q1;
  {
    const float* xq = x + ((size_t)v << 6) + (c << 3);
    const float4 qa = *(const float4*)xq;
    const float4 qb = *(const float4*)(xq + 4);
    float qp[8];
#pragma unroll
    for (int i = 0; i < 8; ++i) {
      const float* wq = &sW[((i << 3) + c) << 3];
      const float4 wa = *(const float4*)wq;
      const float4 wb = *(const float4*)(wq + 4);
      qp[i] = wa.x*qa.x + wa.y*qa.y + wa.z*qa.z + wa.w*qa.w
            + wb.x*qb.x + wb.y*qb.y + wb.z*qb.z + wb.w*qb.w;
    }
    Q1 = rs8(qp, c);
  }

  // ---- stage ptm[v] into LDS as bf16, swizzled units (unit = i^n8) ----
  {
    const float4* p4 = (const float4*)(ptm + (size_t)v * 2048);
#pragma unroll
    for (int t = 0; t < 8; ++t) {
      const int g = lane + (t << 6);
      const float4 val = p4[g];
      const int n  = g >> 4;
      const int ii = (g >> 1) & 7;
      const int hh = g & 1;
      const int unit = (n << 3) | (ii ^ (n & 7));
      *(uint2*)&sFw[(unit << 3) + (hh << 2)] =
          make_uint2(pack_bf2(val.x, val.y), pack_bf2(val.z, val.w));
    }
  }

  wave_lds_fence();   // staging (and sU) complete before reads

  // ---- passes: transport f (LDS), K reduce-scatter, score; f -> LDS bf16 ----
  float s[4];
  const float* xb0 = x + ((size_t)nbv[0] << 6) + (c << 3);
  float4 xa = *(const float4*)xb0;
  float4 xc = *(const float4*)(xb0 + 4);
#pragma unroll
  for (int p = 0; p < 4; ++p) {
    float4 xan, xcn;
    if (p < 3) {
      const float* xbn = x + ((size_t)nbv[p + 1] << 6) + (c << 3);
      xan = *(const float4*)xbn;
      xcn = *(const float4*)(xbn + 4);
    }
    const int rowb = ((p << 3) + n8) << 3;
    float fv[8];
#pragma unroll
    for (int i = 0; i < 8; ++i) {
      const uint4 r = *(const uint4*)&sFw[(rowb | (i ^ n8)) << 3];
      const float p0 = bf_lo(r.x), p1 = bf_hi(r.x);
      const float p2 = bf_lo(r.y), p3 = bf_hi(r.y);
      const float p4v = bf_lo(r.z), p5 = bf_hi(r.z);
      const float p6 = bf_lo(r.w), p7 = bf_hi(r.w);
      fv[i] = p0*xa.x + p1*xa.y + p2*xa.z + p3*xa.w
            + p4v*xc.x + p5*xc.y + p6*xc.z + p7*xc.w;
    }
    float kp[8];
#pragma unroll
    for (int i = 0; i < 8; ++i) {
      const float* wk = &sW[512 + (((i << 3) + c) << 3)];
      const float4 wa = *(const float4*)wk;
      const float4 wb = *(const float4*)(wk + 4);
      kp[i] = wa.x*fv[0] + wa.y*fv[1] + wa.z*fv[2] + wa.w*fv[3]
            + wb.x*fv[4] + wb.y*fv[5] + wb.z*fv[6] + wb.w*fv[7];
    }
    const float K1 = rs8(kp, c);
    float sc = fmaxf(Q1 + K1, 0.0f);
    sc += __shfl_xor(sc, 1);
    sc += __shfl_xor(sc, 2);
    sc += __shfl_xor(sc, 4);
    s[p] = ((mkbits >> p) & 1) ? sc * 0.125f : 0.0f;

    // write f (bf16) over the consumed ptm row, unit (c^n8)
    uint4 w;
    w.x = pack_bf2(fv[0], fv[1]);
    w.y = pack_bf2(fv[2], fv[3]);
    w.z = pack_bf2(fv[4], fv[5]);
    w.w = pack_bf2(fv[6], fv[7]);
    *(uint4*)&sFw[(rowb | (c ^ n8)) << 3] = w;

    if (p < 3) { xa = xan; xc = xcn; }
    pass_sched_fence();
  }

  // ---- attention normalization ----
  float dt = s[0] + s[1] + s[2] + s[3];
  dt += __shfl_xor(dt, 8);
  dt += __shfl_xor(dt, 16);
  dt += __shfl_xor(dt, 32);
  const float rden = 1.0f / fmaxf(dt, 1e-8f);
#pragma unroll
  for (int p = 0; p < 4; ++p) s[p] *= rden;   // s[p] = att

  wave_lds_fence();   // f writes visible before value re-reads

  // ---- value path: reduce-scatter form (49 shuffles total) ----
  float zacc[8];
#pragma unroll
  for (int i = 0; i < 8; ++i) zacc[i] = 0.0f;
#pragma unroll
  for (int hlf = 0; hlf < 2; ++hlf) {
    float t0[8], t1[8], t2[8];
#pragma unroll
    for (int j = 0; j < 8; ++j) { t0[j] = 0.0f; t1[j] = 0.0f; t2[j] = 0.0f; }
#pragma unroll
    for (int p = 0; p < 4; ++p) {
      const uint4 r = *(const uint4*)&sFw[(((((p << 3) + n8) << 3)) | (c ^ n8)) << 3];
      float fj[8];
      fj[0] = bf_lo(r.x); fj[1] = bf_hi(r.x);
      fj[2] = bf_lo(r.y); fj[3] = bf_hi(r.y);
      fj[4] = bf_lo(r.z); fj[5] = bf_hi(r.z);
      fj[6] = bf_lo(r.w); fj[7] = bf_hi(r.w);
      const float2 uu = *(const float2*)&sUw[((p << 3) + n8) << 1];
      const float a = s[p];
      float cf0, cf1, cf2;
      if (hlf == 0) { cf0 = a;                  cf1 = a * uu.x;               cf2 = a * uu.y; }
      else          { cf0 = a * uu.x * uu.x;    cf1 = 2.0f * a * uu.x * uu.y; cf2 = a * uu.y * uu.y; }
#pragma unroll
      for (int j = 0; j < 8; ++j) {
        t0[j] += cf0 * fj[j];
        t1[j] += cf1 * fj[j];
        t2[j] += cf2 * fj[j];
      }
    }
    const float h0 = rs8n(t0, n8);   // = h_{ob+0}[c, j=n8]
    const float h1 = rs8n(t1, n8);
    const float h2 = rs8n(t2, n8);
    const int ob = hlf * 3;
    // WV_o[c][i][j=n8] lives at row (i*8+c), stride 9: offset i*72 + c*9 + n8
    const float* wv0 = &sW[1024 + (ob + 0)*576 + c*9 + n8];
    const float* wv1 = &sW[1024 + (ob + 1)*576 + c*9 + n8];
    const float* wv2 = &sW[1024 + (ob + 2)*576 + c*9 + n8];
#pragma unroll
    for (int i = 0; i < 8; ++i)
      zacc[i] += wv0[i*72]*h0 + wv1[i*72]*h1 + wv2[i*72]*h2;
  }
  const float outv = rs8n(zacc, n8);   // out[c, i=n8]
  out[((size_t)v << 6) + (c << 3) + n8] = outv;
}

extern "C" void kernel_launch(void* const* d_in, const int* in_sizes, int n_in,
                              void* d_out, int out_size, void* d_ws, size_t ws_size,
                              hipStream_t stream) {
  const float* x   = (const float*)d_in[0];
  const int*   nb  = (const int*)d_in[1];
  const void*  msk = d_in[2];
  const float* ptm = (const float*)d_in[3];
  const float* rpu = (const float*)d_in[4];
  const float* rb  = (const float*)d_in[5];
  const float* qc  = (const float*)d_in[6];
  const float* kc  = (const float*)d_in[7];
  const float* vb0 = (const float*)d_in[8];
  const float* vb1 = (const float*)d_in[9];
  const float* vb2 = (const float*)d_in[10];
  const float* vp0 = (const float*)d_in[11];
  const float* vp1 = (const float*)d_in[12];
  const float* vp2 = (const float*)d_in[13];
  (void)in_sizes; (void)n_in; (void)out_size; (void)d_ws; (void)ws_size;

  ge_attn<<<NVERT / 4, 256, 0, stream>>>(x, nb, msk, ptm, rpu, rb, qc, kc,
                                         vb0, vb1, vb2, vp0, vp1, vp2,
                                         (float*)d_out);
}